// Round 4
// baseline (203.987 us; speedup 1.0000x reference)
//
#include <hip/hip_runtime.h>

#define HH 4096      // canvas side
#define KK 32        // box / tile side
#define OH 4065      // HH - KK + 1
#define WPS 96       // output cols per wave-slab (even -> float2-aligned loads)
#define NCOLS 128    // input cols read per wave (2 per lane)
#define RCH 64       // output rows per wave
#define PF 8         // software prefetch depth in rows (16 loads in flight)

// Wave-autonomous design (R3/R4): R0-R2 showed the 4-wave barrier-lockstep
// block is pinned at ~86us regardless of occupancy (31/46/66%). This version
// has ZERO inter-wave barriers: vertical 32-window = per-lane register ring
// (static indices via 32-step unroll), horizontal 32-window = shfl_down
// pair-sum doubling tree. 8-row prefetch keeps 16 load-instrs (8KB/wave)
// permanently in flight; 2752 waves = 10.75/CU -> ~86KB/CU outstanding,
// comfortably past the ~20KB Little's-law threshold for 6.3 TB/s.
// (R4 = identical resubmit of R3: container failed twice = infra flake;
//  bounds/shuffle/ring algebra re-audited clean, so measuring as-is.)
__global__ __launch_bounds__(64) void som_wave(
    const float* __restrict__ img,   // 32x32
    const float* __restrict__ som,   // 4096x4096
    const float* __restrict__ var,   // 4096x4096
    float* __restrict__ out)         // 4065x4065
{
    __shared__ float simg[KK * KK];  // 4 KB, read-only after init
    const int l = threadIdx.x;       // 0..63
    for (int i = l; i < KK * KK; i += 64) simg[i] = img[i];
    __syncthreads();                 // once; single wave, nearly free

    const int slab  = blockIdx.x;            // 0..42
    const int r0    = blockIdx.y * RCH;      // 0..4032 (multiple of 64)
    const int cbase = slab * WPS;            // even
    const int c0    = cbase + 2 * l;         // this lane's even column
    const int c0c   = c0 <= HH - 2 ? c0 : HH - 2;  // float2-safe clamp; clamped
                                             // lanes feed only masked outputs
    const int jc0   = c0c & (KK - 1);        // even -> simg float2 is 8B-aligned
    // store masks (per-lane constants): within-slab col < WPS and global < OH
    const bool maskE = (l <= 47) && (c0     <= OH - 1);
    const bool maskO = (l <= 47) && (c0 + 1 <= OH - 1);
    const int  rlimit = (r0 + RCH - 1 < OH - 1) ? r0 + RCH - 1 : OH - 1;

    // 32-bit byte offsets, SGPR-base + VGPR-voffset addressing
    unsigned voff = (unsigned)(r0 * HH + c0c) * 4u;
    const unsigned vmax  = (unsigned)((HH - 1) * HH + c0c) * 4u;  // row clamp
    const unsigned vstep = HH * 4u;
    unsigned vstore = (unsigned)(r0 * OH + c0) * 4u;

    // ---- prologue: fill prefetch pipe with rows r0 .. r0+PF-1 ----
    float2 pfs[PF], pfv[PF];
#pragma unroll
    for (int p = 0; p < PF; ++p) {
        pfs[p] = *(const float2*)((const char*)som + voff);
        pfv[p] = *(const float2*)((const char*)var + voff);
        voff = (voff + vstep <= vmax) ? voff + vstep : vmax;
    }

    float ring0[KK], ring1[KK];      // static-indexed -> stays in VGPRs
    float sum0 = 0.f, sum1 = 0.f;

    // ---- init peel: steps ir = 0..31 (input rows r0+ir); emit only ir==31 ----
#pragma unroll
    for (int k = 0; k < KK; ++k) {
        const int slot = k & (PF - 1);
        const float2 s2 = pfs[slot];
        const float2 v2 = pfv[slot];
        // refill slot with row r0+k+PF (clamped; clamped rows feed masked rows)
        pfs[slot] = *(const float2*)((const char*)som + voff);
        pfv[slot] = *(const float2*)((const char*)var + voff);
        voff = (voff + vstep <= vmax) ? voff + vstep : vmax;

        const float2 im = *(const float2*)&simg[(k << 5) | jc0]; // (r0+k)%32==k
        const float e0 = im.x - s2.x;
        const float d0 = e0 * e0 * __builtin_amdgcn_rcpf(v2.x + 1e-8f);
        const float e1 = im.y - s2.y;
        const float d1 = e1 * e1 * __builtin_amdgcn_rcpf(v2.y + 1e-8f);
        const float V0 = sum0 + d0;
        const float V1 = sum1 + d1;
        if (k == KK - 1) {
            // emit output row r0 (j = 0)
            float pr = V0 + V1;                       // pair sum: V[2l]+V[2l+1]
            pr += __shfl_down(pr, 1, 64);
            pr += __shfl_down(pr, 2, 64);
            pr += __shfl_down(pr, 4, 64);
            pr += __shfl_down(pr, 8, 64);             // 16 pairs = 32-col window
            const float ev = pr;                      // out col c0
            const float od = ev - V0 + __shfl_down(V0, 16, 64); // out col c0+1
            if (maskE) *(float*)((char*)out + vstore)     = ev;
            if (maskO) *(float*)((char*)out + vstore + 4) = od;
            vstore += OH * 4u;
            sum0 = V0 - ring0[0];                     // drop row r0
            sum1 = V1 - ring1[0];
        } else {
            sum0 = V0;
            sum1 = V1;
        }
        ring0[k] = d0;
        ring1[k] = d1;
    }

    // ---- main: o = 1..2, steps ir = o*32+k; emit row rout = r0+ir-31 ----
#pragma unroll 1
    for (int o = 1; o < 3; ++o) {
#pragma unroll
        for (int k = 0; k < KK; ++k) {
            const int slot = k & (PF - 1);
            const float2 s2 = pfs[slot];
            const float2 v2 = pfv[slot];
            pfs[slot] = *(const float2*)((const char*)som + voff);
            pfv[slot] = *(const float2*)((const char*)var + voff);
            voff = (voff + vstep <= vmax) ? voff + vstep : vmax;

            const float2 im = *(const float2*)&simg[(k << 5) | jc0];
            const float e0 = im.x - s2.x;
            const float d0 = e0 * e0 * __builtin_amdgcn_rcpf(v2.x + 1e-8f);
            const float e1 = im.y - s2.y;
            const float d1 = e1 * e1 * __builtin_amdgcn_rcpf(v2.y + 1e-8f);
            const float V0 = sum0 + d0;
            const float V1 = sum1 + d1;

            const int rout = r0 + o * KK + k - (KK - 1);
            if (rout <= rlimit) {                     // uniform scalar branch
                float pr = V0 + V1;
                pr += __shfl_down(pr, 1, 64);
                pr += __shfl_down(pr, 2, 64);
                pr += __shfl_down(pr, 4, 64);
                pr += __shfl_down(pr, 8, 64);
                const float ev = pr;
                const float od = ev - V0 + __shfl_down(V0, 16, 64);
                if (maskE) *(float*)((char*)out + vstore)     = ev;
                if (maskO) *(float*)((char*)out + vstore + 4) = od;
            }
            vstore += OH * 4u;
            // slide window: drop row rout (= ring slot (k+1)&31), insert new
            sum0 = V0 - ring0[(k + 1) & (KK - 1)];
            sum1 = V1 - ring1[(k + 1) & (KK - 1)];
            ring0[k] = d0;
            ring1[k] = d1;
        }
    }
}

extern "C" void kernel_launch(void* const* d_in, const int* in_sizes, int n_in,
                              void* d_out, int out_size, void* d_ws, size_t ws_size,
                              hipStream_t stream) {
    (void)in_sizes; (void)n_in; (void)out_size; (void)d_ws; (void)ws_size;
    const float* img = (const float*)d_in[0];   // 32x32
    const float* som = (const float*)d_in[1];   // 4096x4096
    const float* var = (const float*)d_in[2];   // 4096x4096
    float* out = (float*)d_out;                 // 4065x4065

    dim3 blk(64);                                // one wave per block
    dim3 grd((OH + WPS - 1) / WPS,               // 43 column slabs
             (OH + RCH - 1) / RCH);              // 64 row chunks
    hipLaunchKernelGGL(som_wave, grd, blk, 0, stream, img, som, var, out);
}